// Round 13
// baseline (6864.215 us; speedup 1.0000x reference)
//
#include <hip/hip_runtime.h>
#include <stdint.h>

// SingleBandLSTM: B=64, IN=16, H=512, T=1024, 2-layer LSTM, constant input per step.
// R13 = R10 (5963us, best) with ONE structural change: L1's step is split into
//   prelude (OFF the h1 recurrence chain): wait f0[t] (L0 runs ~RING ahead, so
//     normally instant) -> stage h0[t] -> ih-MFMA into registers
//   chain: wait f1[t-1] -> stage h1[t-1] (ONE 8-load LLC RTT) -> out-dot ||
//     hh-MFMA (32 MFMAs, accumulate onto prelude regs) -> gbuf -> nonlin ->
//     scattered 4B publish -> drain -> RMW flag.
// Removes from the L1 critical path: one poll, one full staging RTT, 32 MFMAs.
// R12 lesson: keep R10's RMW ready counters (immediate LLC visibility beats
// plain-store flags) and scattered 4B sc1 publishes (u64 stores write-amplify 4x).
// L0 branch is byte-identical to R10.

#define TSEQ 1024
#define HDIM 512
#define BATCH 64
#define RING 8

typedef __attribute__((ext_vector_type(8))) short bf16x8;
typedef __attribute__((ext_vector_type(4))) float f32x4;
typedef __attribute__((ext_vector_type(4))) unsigned int u32x4;

__device__ __forceinline__ unsigned short f2bf(float f) {
  union { float f; unsigned u; } v; v.f = f;
  unsigned r = v.u + 0x7FFFu + ((v.u >> 16) & 1u);   // RNE
  return (unsigned short)(r >> 16);
}
__device__ __forceinline__ float bf2f(unsigned short s) {
  union { unsigned u; float f; } v; v.u = ((unsigned)s) << 16; return v.f;
}
__device__ __forceinline__ float sigm(float x) { return 1.0f / (1.0f + __expf(-x)); }
__device__ __forceinline__ float tanh_(float x) { return 1.0f - 2.0f / (__expf(2.0f * x) + 1.0f); }

__device__ __forceinline__ void flag_add(int* p) {
  __hip_atomic_fetch_add(p, 1, __ATOMIC_RELAXED, __HIP_MEMORY_SCOPE_AGENT);
}
__device__ __forceinline__ void flag_wait(int* p, int target) {
  while (__hip_atomic_load(p, __ATOMIC_RELAXED, __HIP_MEMORY_SCOPE_AGENT) < target)
    __builtin_amdgcn_s_sleep(1);
}

// 64KB global (bf16 [64][512] row-major) -> LDS, XOR swizzle ((row&7)<<4) on byte addr.
// LLC-coherent coalesced loads: 8x dwordx4 sc1 + vmcnt(0) in ONE asm block (R4-safe).
__device__ __forceinline__ void stage64k(char* lds, const unsigned short* src, int tid) {
  u32x4 r0, r1, r2, r3, r4, r5, r6, r7;
  const char* a = (const char*)src + (size_t)tid * 16;
  asm volatile(
      "global_load_dwordx4 %0, %8, off sc1\n\t"
      "global_load_dwordx4 %1, %9, off sc1\n\t"
      "global_load_dwordx4 %2, %10, off sc1\n\t"
      "global_load_dwordx4 %3, %11, off sc1\n\t"
      "global_load_dwordx4 %4, %12, off sc1\n\t"
      "global_load_dwordx4 %5, %13, off sc1\n\t"
      "global_load_dwordx4 %6, %14, off sc1\n\t"
      "global_load_dwordx4 %7, %15, off sc1\n\t"
      "s_waitcnt vmcnt(0)"
      : "=&v"(r0), "=&v"(r1), "=&v"(r2), "=&v"(r3),
        "=&v"(r4), "=&v"(r5), "=&v"(r6), "=&v"(r7)
      : "v"(a), "v"(a + 8192), "v"(a + 16384), "v"(a + 24576),
        "v"(a + 32768), "v"(a + 40960), "v"(a + 49152), "v"(a + 57344)
      : "memory");
  u32x4 vv[8] = {r0, r1, r2, r3, r4, r5, r6, r7};
  #pragma unroll
  for (int i = 0; i < 8; ++i) {
    int q = tid + i * 512;
    int row = q >> 6, kb = (q & 63) << 4;
    *(u32x4*)(lds + row * 1024 + (kb ^ ((row & 7) << 4))) = vv[i];
  }
}
__device__ __forceinline__ void zero64k(char* lds, int tid) {
  u32x4 z = {0u, 0u, 0u, 0u};
  #pragma unroll
  for (int i = 0; i < 8; ++i) {
    int q = tid + i * 512;
    int row = q >> 6, kb = (q & 63) << 4;
    *(u32x4*)(lds + row * 1024 + (kb ^ ((row & 7) << 4))) = z;
  }
}

// ---------------- precompute kernels ----------------
__global__ void k_fc_in(const float* __restrict__ x, const float* __restrict__ w_in,
                        const float* __restrict__ b_in, float* __restrict__ h_in) {
  int b = blockIdx.x;      // 64
  int j = threadIdx.x;     // 512
  float acc = b_in[j];
  #pragma unroll
  for (int i = 0; i < 16; ++i) acc += x[b * 16 + i] * w_in[j * 16 + i];
  h_in[b * HDIM + j] = acc;
}

__global__ __launch_bounds__(512, 1)
void k_xg0(const float* __restrict__ h_in, const float* __restrict__ w_ih0,
           const float* __restrict__ b_ih0, const float* __restrict__ b_hh0,
           float* __restrict__ xg0) {
  __shared__ float hbuf[64 * 516];
  __shared__ float wbuf[8 * 520];
  int r0 = blockIdx.x * 8;           // 256 blocks x 8 rows = 2048 gate rows
  int tid = threadIdx.x;
  for (int i = 0; i < 64; ++i) {
    int c = tid + i * 512;
    hbuf[(c >> 9) * 516 + (c & 511)] = h_in[c];
  }
  for (int i = 0; i < 8; ++i) {
    int c = tid + i * 512;
    wbuf[(c >> 9) * 520 + (c & 511)] = w_ih0[(size_t)r0 * HDIM + c];
  }
  __syncthreads();
  int b = tid >> 3, rl = tid & 7;
  float acc = 0.f;
  for (int k = 0; k < 512; ++k) acc += hbuf[b * 516 + k] * wbuf[rl * 520 + k];
  int r = r0 + rl;
  xg0[(size_t)b * 2048 + r] = acc + b_ih0[r] + b_hh0[r];
}

// ---------------- persistent recurrence kernel ----------------
__global__ __launch_bounds__(512, 1)
void lstm_persist(const float* __restrict__ w_hh0,
                  const float* __restrict__ w_ih1,
                  const float* __restrict__ w_hh1,
                  const float* __restrict__ b_ih1,
                  const float* __restrict__ b_hh1,
                  const float* __restrict__ w_out,
                  const float* __restrict__ b_out,
                  const float* __restrict__ xg0,
                  unsigned short* __restrict__ h0_ring,
                  unsigned short* __restrict__ h1_ring,
                  int* __restrict__ flags,
                  float* __restrict__ out) {
  __shared__ __align__(16) unsigned short hA[BATCH * HDIM];  // 64KB, swizzled
  __shared__ __align__(16) unsigned short hBt[BATCH * HDIM]; // 64KB, swizzled
  __shared__ float gbuf[BATCH * 68];                         // gate transpose buffer
  char* hAc = (char*)hA;
  char* hBc = (char*)hBt;

  const int tid = threadIdx.x;
  const int layer = blockIdx.x & 1;
  const int p = blockIdx.x >> 1;      // 0..31 within group
  const int u0 = p * 16;              // first owned hidden unit

  const int wave = tid >> 6, lane = tid & 63;
  const int nt = wave & 3;            // N-tile (16 gate rows)
  const int mh = wave >> 2;           // M-tile pair selector
  const int ln15 = lane & 15, lg = lane >> 4;

  // slice row ordering: n_local = unit_local*4 + gate  (gate: 0=i,1=f,2=g,3=o)
  const int n_local = nt * 16 + ln15;
  const int grow = (n_local & 3) * HDIM + u0 + (n_local >> 2);  // global gate row

  int* h0_ready = flags;
  int* h0_done  = flags + TSEQ;
  int* h1_ready = flags + 2 * TSEQ;
  int* h1_done  = flags + 3 * TSEQ;

  // ---- weight fragments into registers (fp32 -> bf16) ----
  bf16x8 wh[16];  // w_hh (layer 0 or 1)
  bf16x8 wi[16];  // w_ih1 (layer 1 only)
  {
    const float* Wh = (layer == 0 ? w_hh0 : w_hh1) + (size_t)grow * HDIM;
    #pragma unroll
    for (int kt = 0; kt < 16; ++kt) {
      const float* s = Wh + kt * 32 + lg * 8;
      bf16x8 r;
      #pragma unroll
      for (int e = 0; e < 8; ++e) r[e] = (short)f2bf(s[e]);
      wh[kt] = r;
    }
  }
  if (layer == 1) {
    const float* Wi = w_ih1 + (size_t)grow * HDIM;
    #pragma unroll
    for (int kt = 0; kt < 16; ++kt) {
      const float* s = Wi + kt * 32 + lg * 8;
      bf16x8 r;
      #pragma unroll
      for (int e = 0; e < 8; ++e) r[e] = (short)f2bf(s[e]);
      wi[kt] = r;
    }
  }

  // ---- accumulator init (xg0 fragment for L0; bias for L1) ----
  f32x4 init0, init1;
  if (layer == 0) {
    #pragma unroll
    for (int r = 0; r < 4; ++r) {
      init0[r] = xg0[(size_t)(mh * 32 + lg * 4 + r) * 2048 + grow];
      init1[r] = xg0[(size_t)(mh * 32 + 16 + lg * 4 + r) * 2048 + grow];
    }
  } else {
    float bv = b_ih1[grow] + b_hh1[grow];
    #pragma unroll
    for (int r = 0; r < 4; ++r) { init0[r] = bv; init1[r] = bv; }
  }

  // cell state for this thread's two (batch,unit) pairs
  float c0 = 0.f, c1 = 0.f;
  const int pb = tid >> 3;            // batch of pair
  const int pu = (tid << 1) & 15;     // unit_local (even)

  const int r0 = mh * 32 + ln15, r1 = r0 + 16;
  const int x0 = (r0 & 7) << 4, x1 = (r1 & 7) << 4;

  if (layer == 0) {
    for (int t = 0; t < TSEQ; ++t) {
      if (t > 0) {
        if (tid == 0) flag_wait(&h0_ready[t - 1], 32);
        __syncthreads();
        stage64k(hAc, h0_ring + (size_t)((t - 1) & (RING - 1)) * (BATCH * HDIM), tid);
        __syncthreads();
        if (tid == 0) flag_add(&h0_done[t - 1]);
      } else {
        zero64k(hAc, tid);
        __syncthreads();
      }
      f32x4 a0 = init0, a1 = init1;
      #pragma unroll
      for (int kt = 0; kt < 16; ++kt) {
        const int kb = kt * 64 + lg * 16;
        bf16x8 ha0 = *(const bf16x8*)(hAc + r0 * 1024 + (kb ^ x0));
        bf16x8 ha1 = *(const bf16x8*)(hAc + r1 * 1024 + (kb ^ x1));
        a0 = __builtin_amdgcn_mfma_f32_16x16x32_bf16(ha0, wh[kt], a0, 0, 0, 0);
        a1 = __builtin_amdgcn_mfma_f32_16x16x32_bf16(ha1, wh[kt], a1, 0, 0, 0);
      }
      #pragma unroll
      for (int r = 0; r < 4; ++r) {
        gbuf[(mh * 32 + lg * 4 + r) * 68 + n_local] = a0[r];
        gbuf[(mh * 32 + 16 + lg * 4 + r) * 68 + n_local] = a1[r];
      }
      if (t >= RING && tid == 0) flag_wait(&h0_done[t - RING], 64);
      __syncthreads();
      {
        f32x4 gA = *(const f32x4*)&gbuf[pb * 68 + pu * 4];
        f32x4 gB = *(const f32x4*)&gbuf[pb * 68 + pu * 4 + 4];
        float i0 = sigm(gA[0]), f0 = sigm(gA[1]), z0 = tanh_(gA[2]), o0 = sigm(gA[3]);
        float i1 = sigm(gB[0]), f1 = sigm(gB[1]), z1 = tanh_(gB[2]), o1 = sigm(gB[3]);
        c0 = f0 * c0 + i0 * z0;
        c1 = f1 * c1 + i1 * z1;
        float hv0 = o0 * tanh_(c0), hv1 = o1 * tanh_(c1);
        unsigned pk = (unsigned)f2bf(hv0) | ((unsigned)f2bf(hv1) << 16);
        unsigned short* slot = h0_ring + (size_t)(t & (RING - 1)) * (BATCH * HDIM);
        __hip_atomic_store((unsigned*)(slot + pb * HDIM + u0 + pu), pk,
                           __ATOMIC_RELAXED, __HIP_MEMORY_SCOPE_AGENT);
      }
      __syncthreads();   // implicit vmcnt(0): all sc1 h-stores visible at LLC
      if (tid == 0) flag_add(&h0_ready[t]);
    }
  } else {
    for (int t = 0; t < TSEQ; ++t) {
      // ===== prelude (off the h1 chain): h0[t] stage + ih-MFMA =====
      if (tid == 0) flag_wait(&h0_ready[t], 32);
      __syncthreads();                                            // P1
      stage64k(hAc, h0_ring + (size_t)(t & (RING - 1)) * (BATCH * HDIM), tid);
      __syncthreads();                                            // P2
      if (tid == 0) flag_add(&h0_done[t]);

      f32x4 a0 = init0, a1 = init1;
      #pragma unroll
      for (int kt = 0; kt < 16; ++kt) {
        const int kb = kt * 64 + lg * 16;
        bf16x8 ia0 = *(const bf16x8*)(hAc + r0 * 1024 + (kb ^ x0));
        bf16x8 ia1 = *(const bf16x8*)(hAc + r1 * 1024 + (kb ^ x1));
        a0 = __builtin_amdgcn_mfma_f32_16x16x32_bf16(ia0, wi[kt], a0, 0, 0, 0);
        a1 = __builtin_amdgcn_mfma_f32_16x16x32_bf16(ia1, wi[kt], a1, 0, 0, 0);
      }

      // ===== chain: h1[t-1] stage + out-dot + hh-MFMA + nonlin + publish =====
      if (tid == 0) {
        if (t > 0) flag_wait(&h1_ready[t - 1], 32);
        if (t >= RING) flag_wait(&h1_done[t - RING], 32);  // ring backpressure
      }
      __syncthreads();                                            // P3
      if (t > 0)
        stage64k(hBc, h1_ring + (size_t)((t - 1) & (RING - 1)) * (BATCH * HDIM), tid);
      else
        zero64k(hBc, tid);
      __syncthreads();                                            // P4
      if (tid == 0 && t > 0) flag_add(&h1_done[t - 1]);

      // out_{t-1} from h1 tile (16 threads of wave 0; other waves run MFMA)
      if (t > 0 && tid < 16) {
        const int b = 2 * p + (tid >> 3), seg = tid & 7;
        const int xb = (b & 7) << 4;
        float acc = 0.f;
        #pragma unroll
        for (int i = 0; i < 8; ++i) {
          const int kb = seg * 128 + i * 16;
          bf16x8 hv = *(const bf16x8*)(hBc + b * 1024 + (kb ^ xb));
          const float* wo = w_out + (kb >> 1);
          #pragma unroll
          for (int e = 0; e < 8; ++e) acc += bf2f((unsigned short)hv[e]) * wo[e];
        }
        acc += __shfl_down(acc, 4, 8);
        acc += __shfl_down(acc, 2, 8);
        acc += __shfl_down(acc, 1, 8);
        if (seg == 0) out[b * TSEQ + (t - 1)] = acc + b_out[0];
      }

      #pragma unroll
      for (int kt = 0; kt < 16; ++kt) {
        const int kb = kt * 64 + lg * 16;
        bf16x8 ha0 = *(const bf16x8*)(hBc + r0 * 1024 + (kb ^ x0));
        bf16x8 ha1 = *(const bf16x8*)(hBc + r1 * 1024 + (kb ^ x1));
        a0 = __builtin_amdgcn_mfma_f32_16x16x32_bf16(ha0, wh[kt], a0, 0, 0, 0);
        a1 = __builtin_amdgcn_mfma_f32_16x16x32_bf16(ha1, wh[kt], a1, 0, 0, 0);
      }
      #pragma unroll
      for (int r = 0; r < 4; ++r) {
        gbuf[(mh * 32 + lg * 4 + r) * 68 + n_local] = a0[r];
        gbuf[(mh * 32 + 16 + lg * 4 + r) * 68 + n_local] = a1[r];
      }
      __syncthreads();                                            // P5
      {
        f32x4 gA = *(const f32x4*)&gbuf[pb * 68 + pu * 4];
        f32x4 gB = *(const f32x4*)&gbuf[pb * 68 + pu * 4 + 4];
        float i0 = sigm(gA[0]), f0 = sigm(gA[1]), z0 = tanh_(gA[2]), o0 = sigm(gA[3]);
        float i1 = sigm(gB[0]), f1 = sigm(gB[1]), z1 = tanh_(gB[2]), o1 = sigm(gB[3]);
        c0 = f0 * c0 + i0 * z0;
        c1 = f1 * c1 + i1 * z1;
        float hv0 = o0 * tanh_(c0), hv1 = o1 * tanh_(c1);
        unsigned pk = (unsigned)f2bf(hv0) | ((unsigned)f2bf(hv1) << 16);
        unsigned short* slot = h1_ring + (size_t)(t & (RING - 1)) * (BATCH * HDIM);
        __hip_atomic_store((unsigned*)(slot + pb * HDIM + u0 + pu), pk,
                           __ATOMIC_RELAXED, __HIP_MEMORY_SCOPE_AGENT);
      }
      __syncthreads();   // P6: implicit vmcnt(0): sc1 h-stores visible at LLC
      if (tid == 0) flag_add(&h1_ready[t]);
    }
    // epilogue: out_{T-1}
    if (tid == 0) flag_wait(&h1_ready[TSEQ - 1], 32);
    __syncthreads();
    stage64k(hBc, h1_ring + (size_t)((TSEQ - 1) & (RING - 1)) * (BATCH * HDIM), tid);
    __syncthreads();
    if (tid < 16) {
      const int b = 2 * p + (tid >> 3), seg = tid & 7;
      const int xb = (b & 7) << 4;
      float acc = 0.f;
      #pragma unroll
      for (int i = 0; i < 8; ++i) {
        const int kb = seg * 128 + i * 16;
        bf16x8 hv = *(const bf16x8*)(hBc + b * 1024 + (kb ^ xb));
        const float* wo = w_out + (kb >> 1);
        #pragma unroll
        for (int e = 0; e < 8; ++e) acc += bf2f((unsigned short)hv[e]) * wo[e];
      }
      acc += __shfl_down(acc, 4, 8);
      acc += __shfl_down(acc, 2, 8);
      acc += __shfl_down(acc, 1, 8);
      if (seg == 0) out[b * TSEQ + (TSEQ - 1)] = acc + b_out[0];
    }
  }
}

extern "C" void kernel_launch(void* const* d_in, const int* in_sizes, int n_in,
                              void* d_out, int out_size, void* d_ws, size_t ws_size,
                              hipStream_t stream) {
  (void)in_sizes; (void)n_in; (void)out_size; (void)ws_size;
  const float* x     = (const float*)d_in[0];
  const float* w_in  = (const float*)d_in[1];
  const float* b_in  = (const float*)d_in[2];
  const float* w_ih0 = (const float*)d_in[3];
  const float* w_hh0 = (const float*)d_in[4];
  const float* b_ih0 = (const float*)d_in[5];
  const float* b_hh0 = (const float*)d_in[6];
  const float* w_ih1 = (const float*)d_in[7];
  const float* w_hh1 = (const float*)d_in[8];
  const float* b_ih1 = (const float*)d_in[9];
  const float* b_hh1 = (const float*)d_in[10];
  const float* w_out = (const float*)d_in[11];
  const float* b_out = (const float*)d_in[12];

  char* ws = (char*)d_ws;
  unsigned short* h0_ring = (unsigned short*)(ws + 0);          // 512KB
  unsigned short* h1_ring = (unsigned short*)(ws + 524288);     // 512KB
  float* xg0  = (float*)(ws + 1048576);                         // 512KB
  float* h_in = (float*)(ws + 1572864);                         // 128KB
  int*   flags = (int*)(ws + 1703936);                          // 16KB

  hipMemsetAsync(flags, 0, 4 * TSEQ * sizeof(int), stream);
  k_fc_in<<<64, 512, 0, stream>>>(x, w_in, b_in, h_in);
  k_xg0<<<256, 512, 0, stream>>>(h_in, w_ih0, b_ih0, b_hh0, xg0);
  lstm_persist<<<64, 512, 0, stream>>>(w_hh0, w_ih1, w_hh1, b_ih1, b_hh1,
                                       w_out, b_out, xg0, h0_ring, h1_ring,
                                       flags, (float*)d_out);
}